// Round 1
// baseline (167.889 us; speedup 1.0000x reference)
//
#include <hip/hip_runtime.h>
#include <hip/hip_bf16.h>

// Problem constants
#define N_   2000
#define NP   2048   // padded rows
#define F_   64
#define T_   24

typedef short  v8s  __attribute__((ext_vector_type(8)));   // 8 bf16 (4 VGPRs) MFMA frag
typedef float  v4f  __attribute__((ext_vector_type(4)));   // MFMA C/D frag
typedef unsigned short v4us __attribute__((ext_vector_type(4)));

__device__ __forceinline__ unsigned short f2bf(float f) {
  unsigned int u = __float_as_uint(f);
  u += 0x7fffu + ((u >> 16) & 1u);     // RNE
  return (unsigned short)(u >> 16);
}

// ---------------------------------------------------------------------------
// Kernel 1: build Z1 (normalized rows) in bf16, layout zb[t][n][f], n padded
// to 2048 with zero rows. One block per n (grid 2048).
// ---------------------------------------------------------------------------
__global__ __launch_bounds__(256) void fill_z(const float* __restrict__ x,
                                              unsigned short* __restrict__ zb) {
  int n = blockIdx.x;
  int tid = threadIdx.x, wave = tid >> 6, lane = tid & 63;
  if (n >= N_) {                    // zero padding rows for every t
    for (int t = wave; t < T_; t += 4) zb[(t * NP + n) * F_ + lane] = 0;
    return;
  }
  __shared__ float xs[F_ * 25];     // padded stride 25 to break bank conflicts
  const float* xn = x + n * (F_ * T_);
  for (int i = tid; i < F_ * T_; i += 256)
    xs[(i / T_) * 25 + (i % T_)] = xn[i];
  __syncthreads();
  for (int t = wave; t < T_; t += 4) {
    float v = xs[lane * 25 + t];    // f = lane
    float ss = v * v;
    #pragma unroll
    for (int m = 1; m < 64; m <<= 1) ss += __shfl_xor(ss, m);
    float nrm = fmaxf(sqrtf(ss), 1e-12f);
    zb[(t * NP + n) * F_ + lane] = f2bf(v / nrm);
  }
}

// ---------------------------------------------------------------------------
// Kernel 2: wT[m][fout][fin] = bf16(W_m[fin][fout])  (B-operand layout)
// ---------------------------------------------------------------------------
__global__ __launch_bounds__(256) void prep_wT(const float* __restrict__ wq,
                                               const float* __restrict__ wk,
                                               const float* __restrict__ wv,
                                               unsigned short* __restrict__ wT) {
  const float* src = (blockIdx.x == 0) ? wq : (blockIdx.x == 1) ? wk : wv;
  unsigned short* dst = wT + blockIdx.x * 4096;
  for (int i = threadIdx.x; i < 4096; i += 256) {
    int fi = i >> 6, fo = i & 63;          // src[fi][fo]
    dst[fo * 64 + fi] = f2bf(src[i]);
  }
}

// ---------------------------------------------------------------------------
// Kernel 3: diag_w[f] = sum_p weight[p][f][f].  One block per f.
// ---------------------------------------------------------------------------
__global__ __launch_bounds__(256) void diag_w_k(const float* __restrict__ w,
                                                float* __restrict__ dw) {
  int f = blockIdx.x, tid = threadIdx.x;
  float s = 0.f;
  for (int p = tid; p < N_; p += 256) s += w[p * (F_ * F_) + f * (F_ + 1)];
  #pragma unroll
  for (int m = 1; m < 64; m <<= 1) s += __shfl_xor(s, m);
  __shared__ float red[4];
  if ((tid & 63) == 0) red[tid >> 6] = s;
  __syncthreads();
  if (tid == 0) dw[f] = red[0] + red[1] + red[2] + red[3];
}

// ---------------------------------------------------------------------------
// Kernel 4: the heavy one. For each t: rowsum[t][r] += sum_c exp(Z1_t[r]·Z1_t[c] - 1)
// Grid (8 rowblocks, 4 colblocks, 24 t), block 256 = 4 waves.
// Each wave: 64 rows (4 rowgroups x 16), iterates 16-col tiles over its col range.
// 16x16x32 bf16 MFMA, exp-accumulate in registers, shuffle-reduce, atomicAdd.
// ---------------------------------------------------------------------------
__global__ __launch_bounds__(256) void gram_expsum(const unsigned short* __restrict__ zb,
                                                   float* __restrict__ rowsum) {
  int rb = blockIdx.x, cb = blockIdx.y, t = blockIdx.z;
  int wave = threadIdx.x >> 6, lane = threadIdx.x & 63;
  int lr = lane & 15, lk = (lane >> 4) * 8;
  const unsigned short* z = zb + t * (NP * F_);
  int r0 = rb * 256 + wave * 64;

  v8s a[4][2];
  #pragma unroll
  for (int rg = 0; rg < 4; rg++)
    #pragma unroll
    for (int kb = 0; kb < 2; kb++)
      a[rg][kb] = *(const v8s*)(z + (r0 + rg * 16 + lr) * F_ + kb * 32 + lk);

  float acc[16];
  #pragma unroll
  for (int i = 0; i < 16; i++) acc[i] = 0.f;

  int c0 = cb * 512, c1 = (cb == 3) ? N_ : c0 + 512;   // 2000 = 125*16, exact tiles
  const unsigned short* bp = z + (c0 + lr) * F_ + lk;
  v4f cz = {0.f, 0.f, 0.f, 0.f};

  for (int c = c0; c < c1; c += 16) {
    v8s b0 = *(const v8s*)(bp);
    v8s b1 = *(const v8s*)(bp + 32);
    bp += 16 * F_;
    #pragma unroll
    for (int rg = 0; rg < 4; rg++) {
      v4f C = __builtin_amdgcn_mfma_f32_16x16x32_bf16(a[rg][0], b0, cz, 0, 0, 0);
      C = __builtin_amdgcn_mfma_f32_16x16x32_bf16(a[rg][1], b1, C, 0, 0, 0);
      #pragma unroll
      for (int i = 0; i < 4; i++) acc[rg * 4 + i] += __expf(C[i] - 1.0f);
    }
  }
  // reduce across the 16 lanes sharing (lane>>4): cols live in lane&15
  #pragma unroll
  for (int i = 0; i < 16; i++) {
    acc[i] += __shfl_xor(acc[i], 1);
    acc[i] += __shfl_xor(acc[i], 2);
    acc[i] += __shfl_xor(acc[i], 4);
    acc[i] += __shfl_xor(acc[i], 8);
  }
  if (lr == 0) {
    float* rs = rowsum + t * NP;
    #pragma unroll
    for (int rg = 0; rg < 4; rg++)
      #pragma unroll
      for (int i = 0; i < 4; i++) {
        int r = r0 + rg * 16 + (lane >> 4) * 4 + i;
        if (r < N_) atomicAdd(&rs[r], acc[rg * 4 + i]);
      }
  }
}

// ---------------------------------------------------------------------------
// Kernel 5: diag_adj[n] = adj_norm[n][n] * sum_t 1/rowsum[t][n]
// ---------------------------------------------------------------------------
__global__ __launch_bounds__(256) void diag_adj_k(const float* __restrict__ adj,
                                                  const float* __restrict__ rowsum,
                                                  float* __restrict__ da) {
  int n = blockIdx.x * 256 + threadIdx.x;
  if (n >= N_) return;
  float s = 0.f;
  #pragma unroll
  for (int t = 0; t < T_; t++) s += 1.0f / rowsum[t * NP + n];
  da[n] = adj[n * (N_ + 1)] * s;
}

// ---------------------------------------------------------------------------
// Kernel 6: cross-attention per n (one wave each) + final scaled store.
// Per-wave LDS region 16KB: xt[32][64] | q[32][64] | k[32][64] | vT[64][32],
// p[32][32] reuses xt. All bf16. Rows t>=24 zero-padded.
// ---------------------------------------------------------------------------
__global__ __launch_bounds__(256) void cross_attn(const float* __restrict__ x,
                                                  const unsigned short* __restrict__ wT,
                                                  const float* __restrict__ dadj_g,
                                                  const float* __restrict__ dw_g,
                                                  float* __restrict__ out) {
  __shared__ __align__(16) unsigned short lds[4 * 8192];
  int wave = threadIdx.x >> 6, lane = threadIdx.x & 63;
  int n = blockIdx.x * 4 + wave;
  unsigned short* xt = lds + wave * 8192;
  unsigned short* q  = xt + 2048;
  unsigned short* k  = xt + 4096;
  unsigned short* vT = xt + 6144;
  unsigned short* p  = xt;                      // reused after phase 1
  int lr = lane & 15, lk = (lane >> 4) * 8;
  int row0q = (lane >> 4) * 4;
  v4f cz = {0.f, 0.f, 0.f, 0.f};

  // ---- load x[n] (F,T) -> xt (T,F) bf16, zero rows 24..31 ----
  const float* xn = x + n * (F_ * T_);
  #pragma unroll
  for (int j = 0; j < 24; j++) {
    int i = j * 64 + lane;
    float v = xn[i];
    xt[(i % T_) * 64 + (i / T_)] = f2bf(v);
  }
  { v8s z8 = {0,0,0,0,0,0,0,0}; *(v8s*)(xt + 24 * 64 + lane * 8) = z8; }

  // ---- phase 1: Q = xt*Wq, K = xt*Wk, V = xt*Wv ----
  v8s xa[2][2];
  #pragma unroll
  for (int rt = 0; rt < 2; rt++)
    #pragma unroll
    for (int kb = 0; kb < 2; kb++)
      xa[rt][kb] = *(const v8s*)(xt + (rt * 16 + lr) * 64 + kb * 32 + lk);

  #pragma unroll
  for (int m = 0; m < 3; m++) {
    const unsigned short* wt = wT + m * 4096;
    unsigned short* dst = (m == 0) ? q : k;
    #pragma unroll
    for (int ct = 0; ct < 4; ct++) {
      v8s b0 = *(const v8s*)(wt + (ct * 16 + lr) * 64 + lk);
      v8s b1 = *(const v8s*)(wt + (ct * 16 + lr) * 64 + 32 + lk);
      int col = ct * 16 + lr;
      #pragma unroll
      for (int rt = 0; rt < 2; rt++) {
        v4f C = __builtin_amdgcn_mfma_f32_16x16x32_bf16(xa[rt][0], b0, cz, 0, 0, 0);
        C = __builtin_amdgcn_mfma_f32_16x16x32_bf16(xa[rt][1], b1, C, 0, 0, 0);
        int r0 = rt * 16 + row0q;
        if (m < 2) {
          #pragma unroll
          for (int i = 0; i < 4; i++) dst[(r0 + i) * 64 + col] = f2bf(C[i]);
        } else {            // V stored transposed: vT[f][s], 4 contiguous bf16
          v4us pk = { f2bf(C[0]), f2bf(C[1]), f2bf(C[2]), f2bf(C[3]) };
          *(v4us*)(vT + col * 32 + r0) = pk;
        }
      }
    }
  }

  // ---- phase 2: scores = Q K^T / 8, softmax over s (mask s>=24), P -> LDS ----
  v8s qa[2][2];
  #pragma unroll
  for (int rt = 0; rt < 2; rt++)
    #pragma unroll
    for (int kb = 0; kb < 2; kb++)
      qa[rt][kb] = *(const v8s*)(q + (rt * 16 + lr) * 64 + kb * 32 + lk);

  float ev[2][2][4];   // [ct][rt][i]
  #pragma unroll
  for (int ct = 0; ct < 2; ct++) {
    v8s b0 = *(const v8s*)(k + (ct * 16 + lr) * 64 + lk);
    v8s b1 = *(const v8s*)(k + (ct * 16 + lr) * 64 + 32 + lk);
    int col = ct * 16 + lr;
    #pragma unroll
    for (int rt = 0; rt < 2; rt++) {
      v4f C = __builtin_amdgcn_mfma_f32_16x16x32_bf16(qa[rt][0], b0, cz, 0, 0, 0);
      C = __builtin_amdgcn_mfma_f32_16x16x32_bf16(qa[rt][1], b1, C, 0, 0, 0);
      #pragma unroll
      for (int i = 0; i < 4; i++)
        ev[ct][rt][i] = (col < T_) ? __expf(C[i] * 0.125f) : 0.0f;
    }
  }
  #pragma unroll
  for (int rt = 0; rt < 2; rt++)
    #pragma unroll
    for (int i = 0; i < 4; i++) {
      float r = ev[0][rt][i] + ev[1][rt][i];
      r += __shfl_xor(r, 1); r += __shfl_xor(r, 2);
      r += __shfl_xor(r, 4); r += __shfl_xor(r, 8);
      float inv = 1.0f / r;
      int row = rt * 16 + row0q + i;
      p[row * 32 + lr]      = f2bf(ev[0][rt][i] * inv);
      p[row * 32 + 16 + lr] = f2bf(ev[1][rt][i] * inv);
    }

  // ---- phase 3: O = P V, scale by diag_adj[n]*diag_w[f], store out[n][f][t] ----
  v8s pa[2];
  #pragma unroll
  for (int rt = 0; rt < 2; rt++)
    pa[rt] = *(const v8s*)(p + (rt * 16 + lr) * 32 + lk);
  float dadj = dadj_g[n];
  float* outn = out + n * (F_ * T_);
  #pragma unroll
  for (int ct = 0; ct < 4; ct++) {
    v8s vb = *(const v8s*)(vT + (ct * 16 + lr) * 32 + lk);
    float sc = dadj * dw_g[ct * 16 + lr];
    #pragma unroll
    for (int rt = 0; rt < 2; rt++) {
      v4f C = __builtin_amdgcn_mfma_f32_16x16x32_bf16(pa[rt], vb, cz, 0, 0, 0);
      int r0 = rt * 16 + row0q;
      if (r0 < T_) {
        v4f o;
        #pragma unroll
        for (int i = 0; i < 4; i++) o[i] = C[i] * sc;
        *(v4f*)(outn + (ct * 16 + lr) * T_ + r0) = o;
      }
    }
  }
}

// ---------------------------------------------------------------------------
extern "C" void kernel_launch(void* const* d_in, const int* in_sizes, int n_in,
                              void* d_out, int out_size, void* d_ws, size_t ws_size,
                              hipStream_t stream) {
  const float* x   = (const float*)d_in[0];
  const float* adj = (const float*)d_in[1];
  const float* w   = (const float*)d_in[2];
  const float* wq  = (const float*)d_in[3];
  const float* wk  = (const float*)d_in[4];
  const float* wv  = (const float*)d_in[5];
  float* out = (float*)d_out;

  char* ws = (char*)d_ws;
  unsigned short* zb     = (unsigned short*)ws;                       // 24*2048*64*2 = 6,291,456
  float*          rowsum = (float*)(ws + 6291456);                    // 24*2048*4   =   196,608
  float*          dadj   = (float*)(ws + 6291456 + 196608);           // 2048*4      =     8,192
  float*          dw     = (float*)(ws + 6291456 + 196608 + 8192);    // 64*4        =       256
  unsigned short* wT     = (unsigned short*)(ws + 6291456 + 196608 + 8192 + 256);  // 24,576

  hipMemsetAsync(rowsum, 0, T_ * NP * sizeof(float), stream);
  hipLaunchKernelGGL(fill_z,      dim3(NP),       dim3(256), 0, stream, x, zb);
  hipLaunchKernelGGL(prep_wT,     dim3(3),        dim3(256), 0, stream, wq, wk, wv, wT);
  hipLaunchKernelGGL(diag_w_k,    dim3(F_),       dim3(256), 0, stream, w, dw);
  hipLaunchKernelGGL(gram_expsum, dim3(8, 4, 24), dim3(256), 0, stream, zb, rowsum);
  hipLaunchKernelGGL(diag_adj_k,  dim3(8),        dim3(256), 0, stream, adj, rowsum, dadj);
  hipLaunchKernelGGL(cross_attn,  dim3(500),      dim3(256), 0, stream, x, wT, dadj, dw, out);
}

// Round 2
// 153.902 us; speedup vs baseline: 1.0909x; 1.0909x over previous
//
#include <hip/hip_runtime.h>
#include <hip/hip_bf16.h>

// Problem constants
#define N_   2000
#define NP   2048   // padded rows
#define F_   64
#define T_   24

typedef short  v8s  __attribute__((ext_vector_type(8)));   // 8 bf16 (4 VGPRs) MFMA frag
typedef float  v4f  __attribute__((ext_vector_type(4)));   // MFMA C/D frag
typedef unsigned short v4us __attribute__((ext_vector_type(4)));

__device__ __forceinline__ unsigned short f2bf(float f) {
  unsigned int u = __float_as_uint(f);
  u += 0x7fffu + ((u >> 16) & 1u);     // RNE
  return (unsigned short)(u >> 16);
}

// ---------------------------------------------------------------------------
// Kernel 1 (fused prep):
//   blocks [0,2048):     fill_z  -> zb[t][n][f] bf16, unit rows, pad n>=2000
//   blocks [2048,2112):  diag_w  -> dw[f] = sum_p weight[p][f][f]
//   block  2112:         prep_wT -> wT[m][fout][fin] bf16 (B-operand layout)
// ---------------------------------------------------------------------------
__global__ __launch_bounds__(256) void prep(const float* __restrict__ x,
                                            const float* __restrict__ w,
                                            const float* __restrict__ wq,
                                            const float* __restrict__ wk,
                                            const float* __restrict__ wv,
                                            unsigned short* __restrict__ zb,
                                            float* __restrict__ dw,
                                            unsigned short* __restrict__ wT) {
  __shared__ float xs[F_ * 25];     // fill_z transpose buffer (stride 25)
  __shared__ float red[4];
  int b = blockIdx.x;
  int tid = threadIdx.x, wave = tid >> 6, lane = tid & 63;

  if (b < NP) {                                   // ---- fill_z ----
    int n = b;
    if (n >= N_) {
      for (int t = wave; t < T_; t += 4) zb[(t * NP + n) * F_ + lane] = 0;
      return;
    }
    const float* xn = x + n * (F_ * T_);
    for (int i = tid; i < F_ * T_; i += 256)
      xs[(i / T_) * 25 + (i % T_)] = xn[i];
    __syncthreads();
    for (int t = wave; t < T_; t += 4) {
      float v = xs[lane * 25 + t];    // f = lane
      float ss = v * v;
      #pragma unroll
      for (int m = 1; m < 64; m <<= 1) ss += __shfl_xor(ss, m);
      float nrm = fmaxf(sqrtf(ss), 1e-12f);
      zb[(t * NP + n) * F_ + lane] = f2bf(v / nrm);
    }
  } else if (b < NP + 64) {                       // ---- diag_w ----
    int f = b - NP;
    float s = 0.f;
    for (int p = tid; p < N_; p += 256) s += w[p * (F_ * F_) + f * (F_ + 1)];
    #pragma unroll
    for (int m = 1; m < 64; m <<= 1) s += __shfl_xor(s, m);
    if (lane == 0) red[wave] = s;
    __syncthreads();
    if (tid == 0) dw[f] = red[0] + red[1] + red[2] + red[3];
  } else {                                        // ---- prep_wT ----
    for (int i = tid; i < 3 * 4096; i += 256) {
      int m = i >> 12, r = i & 4095;
      const float* src = (m == 0) ? wq : (m == 1) ? wk : wv;
      int fi = r >> 6, fo = r & 63;               // src[fi][fo]
      wT[m * 4096 + fo * 64 + fi] = f2bf(src[r]);
    }
  }
}

// ---------------------------------------------------------------------------
// Kernel 2: for each t, colblock cb:
//   partial[cb][t][r] = sum_{c in cb} exp(Z1_t[r]·Z1_t[c] - 1)
// Grid (8 rowblocks, 4 colblocks, 24 t), block 256 = 4 waves.
// Each wave: 64 rows (4 rowgroups x 16), 16-col tiles, 16x16x32 bf16 MFMA,
// exp-accumulate in registers, shuffle-reduce, plain stores (no atomics).
// ---------------------------------------------------------------------------
__global__ __launch_bounds__(256) void gram_expsum(const unsigned short* __restrict__ zb,
                                                   float* __restrict__ partial) {
  int rb = blockIdx.x, cb = blockIdx.y, t = blockIdx.z;
  int wave = threadIdx.x >> 6, lane = threadIdx.x & 63;
  int lr = lane & 15, lk = (lane >> 4) * 8;
  const unsigned short* z = zb + t * (NP * F_);
  int r0 = rb * 256 + wave * 64;

  v8s a[4][2];
  #pragma unroll
  for (int rg = 0; rg < 4; rg++)
    #pragma unroll
    for (int kb = 0; kb < 2; kb++)
      a[rg][kb] = *(const v8s*)(z + (r0 + rg * 16 + lr) * F_ + kb * 32 + lk);

  float acc[16];
  #pragma unroll
  for (int i = 0; i < 16; i++) acc[i] = 0.f;

  int c0 = cb * 512, c1 = (cb == 3) ? N_ : c0 + 512;   // 2000 = 125*16, exact tiles
  const unsigned short* bp = z + (c0 + lr) * F_ + lk;
  v4f cz = {0.f, 0.f, 0.f, 0.f};
  const float INV_E = 0.36787944117144233f;            // exp(C-1) = exp(C)*e^-1

  for (int c = c0; c < c1; c += 16) {
    v8s b0 = *(const v8s*)(bp);
    v8s b1 = *(const v8s*)(bp + 32);
    bp += 16 * F_;
    #pragma unroll
    for (int rg = 0; rg < 4; rg++) {
      v4f C = __builtin_amdgcn_mfma_f32_16x16x32_bf16(a[rg][0], b0, cz, 0, 0, 0);
      C = __builtin_amdgcn_mfma_f32_16x16x32_bf16(a[rg][1], b1, C, 0, 0, 0);
      #pragma unroll
      for (int i = 0; i < 4; i++)
        acc[rg * 4 + i] = fmaf(__expf(C[i]), INV_E, acc[rg * 4 + i]);
    }
  }
  // cols live in lane&15: reduce across those 16 lanes
  #pragma unroll
  for (int i = 0; i < 16; i++) {
    acc[i] += __shfl_xor(acc[i], 1);
    acc[i] += __shfl_xor(acc[i], 2);
    acc[i] += __shfl_xor(acc[i], 4);
    acc[i] += __shfl_xor(acc[i], 8);
  }
  if (lr == 0) {
    float* ps = partial + (cb * T_ + t) * NP;
    #pragma unroll
    for (int rg = 0; rg < 4; rg++)
      #pragma unroll
      for (int i = 0; i < 4; i++)
        ps[r0 + rg * 16 + (lane >> 4) * 4 + i] = acc[rg * 4 + i];
  }
}

// ---------------------------------------------------------------------------
// Kernel 3: cross-attention per n (one wave each) + inline diag_adj + store.
// Per-wave LDS region 16KB: xt[32][64] | q[32][64] | k[32][64] | vT[64][32],
// p[32][32] reuses xt. All bf16. Rows t>=24 zero-padded.
// ---------------------------------------------------------------------------
__global__ __launch_bounds__(256) void cross_attn(const float* __restrict__ x,
                                                  const unsigned short* __restrict__ wT,
                                                  const float* __restrict__ adj,
                                                  const float* __restrict__ partial,
                                                  const float* __restrict__ dw_g,
                                                  float* __restrict__ out) {
  __shared__ __align__(16) unsigned short lds[4 * 8192];
  int wave = threadIdx.x >> 6, lane = threadIdx.x & 63;
  int n = blockIdx.x * 4 + wave;
  unsigned short* xt = lds + wave * 8192;
  unsigned short* q  = xt + 2048;
  unsigned short* k  = xt + 4096;
  unsigned short* vT = xt + 6144;
  unsigned short* p  = xt;                      // reused after phase 1
  int lr = lane & 15, lk = (lane >> 4) * 8;
  int row0q = (lane >> 4) * 4;
  v4f cz = {0.f, 0.f, 0.f, 0.f};

  // ---- diag_adj[n] = adj[n][n] * sum_t 1/(sum_cb partial[cb][t][n]) ----
  float invsum = 0.f;
  if (lane < T_) {
    float s = 0.f;
    #pragma unroll
    for (int cb = 0; cb < 4; cb++) s += partial[(cb * T_ + lane) * NP + n];
    invsum = 1.0f / s;
  }
  #pragma unroll
  for (int m = 1; m < 64; m <<= 1) invsum += __shfl_xor(invsum, m);
  float dadj = adj[n * (N_ + 1)] * invsum;

  // ---- load x[n] (F,T) -> xt (T,F) bf16, zero rows 24..31 ----
  const float* xn = x + n * (F_ * T_);
  #pragma unroll
  for (int j = 0; j < 24; j++) {
    int i = j * 64 + lane;
    float v = xn[i];
    xt[(i % T_) * 64 + (i / T_)] = f2bf(v);
  }
  { v8s z8 = {0,0,0,0,0,0,0,0}; *(v8s*)(xt + 24 * 64 + lane * 8) = z8; }

  // ---- phase 1: Q = xt*Wq, K = xt*Wk, V = xt*Wv ----
  v8s xa[2][2];
  #pragma unroll
  for (int rt = 0; rt < 2; rt++)
    #pragma unroll
    for (int kb = 0; kb < 2; kb++)
      xa[rt][kb] = *(const v8s*)(xt + (rt * 16 + lr) * 64 + kb * 32 + lk);

  #pragma unroll
  for (int m = 0; m < 3; m++) {
    const unsigned short* wt = wT + m * 4096;
    unsigned short* dst = (m == 0) ? q : k;
    #pragma unroll
    for (int ct = 0; ct < 4; ct++) {
      v8s b0 = *(const v8s*)(wt + (ct * 16 + lr) * 64 + lk);
      v8s b1 = *(const v8s*)(wt + (ct * 16 + lr) * 64 + 32 + lk);
      int col = ct * 16 + lr;
      #pragma unroll
      for (int rt = 0; rt < 2; rt++) {
        v4f C = __builtin_amdgcn_mfma_f32_16x16x32_bf16(xa[rt][0], b0, cz, 0, 0, 0);
        C = __builtin_amdgcn_mfma_f32_16x16x32_bf16(xa[rt][1], b1, C, 0, 0, 0);
        int r0 = rt * 16 + row0q;
        if (m < 2) {
          #pragma unroll
          for (int i = 0; i < 4; i++) dst[(r0 + i) * 64 + col] = f2bf(C[i]);
        } else {            // V stored transposed: vT[f][s], 4 contiguous bf16
          v4us pk = { f2bf(C[0]), f2bf(C[1]), f2bf(C[2]), f2bf(C[3]) };
          *(v4us*)(vT + col * 32 + r0) = pk;
        }
      }
    }
  }

  // ---- phase 2: scores = Q K^T / 8, softmax over s (mask s>=24), P -> LDS ----
  v8s qa[2][2];
  #pragma unroll
  for (int rt = 0; rt < 2; rt++)
    #pragma unroll
    for (int kb = 0; kb < 2; kb++)
      qa[rt][kb] = *(const v8s*)(q + (rt * 16 + lr) * 64 + kb * 32 + lk);

  float ev[2][2][4];   // [ct][rt][i]
  #pragma unroll
  for (int ct = 0; ct < 2; ct++) {
    v8s b0 = *(const v8s*)(k + (ct * 16 + lr) * 64 + lk);
    v8s b1 = *(const v8s*)(k + (ct * 16 + lr) * 64 + 32 + lk);
    int col = ct * 16 + lr;
    #pragma unroll
    for (int rt = 0; rt < 2; rt++) {
      v4f C = __builtin_amdgcn_mfma_f32_16x16x32_bf16(qa[rt][0], b0, cz, 0, 0, 0);
      C = __builtin_amdgcn_mfma_f32_16x16x32_bf16(qa[rt][1], b1, C, 0, 0, 0);
      #pragma unroll
      for (int i = 0; i < 4; i++)
        ev[ct][rt][i] = (col < T_) ? __expf(C[i] * 0.125f) : 0.0f;
    }
  }
  #pragma unroll
  for (int rt = 0; rt < 2; rt++)
    #pragma unroll
    for (int i = 0; i < 4; i++) {
      float r = ev[0][rt][i] + ev[1][rt][i];
      r += __shfl_xor(r, 1); r += __shfl_xor(r, 2);
      r += __shfl_xor(r, 4); r += __shfl_xor(r, 8);
      float inv = 1.0f / r;
      int row = rt * 16 + row0q + i;
      p[row * 32 + lr]      = f2bf(ev[0][rt][i] * inv);
      p[row * 32 + 16 + lr] = f2bf(ev[1][rt][i] * inv);
    }

  // ---- phase 3: O = P V, scale by diag_adj[n]*diag_w[f], store out[n][f][t] ----
  v8s pa[2];
  #pragma unroll
  for (int rt = 0; rt < 2; rt++)
    pa[rt] = *(const v8s*)(p + (rt * 16 + lr) * 32 + lk);
  float* outn = out + n * (F_ * T_);
  #pragma unroll
  for (int ct = 0; ct < 4; ct++) {
    v8s vb = *(const v8s*)(vT + (ct * 16 + lr) * 32 + lk);
    float sc = dadj * dw_g[ct * 16 + lr];
    #pragma unroll
    for (int rt = 0; rt < 2; rt++) {
      v4f C = __builtin_amdgcn_mfma_f32_16x16x32_bf16(pa[rt], vb, cz, 0, 0, 0);
      int r0 = rt * 16 + row0q;
      if (r0 < T_) {
        v4f o;
        #pragma unroll
        for (int i = 0; i < 4; i++) o[i] = C[i] * sc;
        *(v4f*)(outn + (ct * 16 + lr) * T_ + r0) = o;
      }
    }
  }
}

// ---------------------------------------------------------------------------
extern "C" void kernel_launch(void* const* d_in, const int* in_sizes, int n_in,
                              void* d_out, int out_size, void* d_ws, size_t ws_size,
                              hipStream_t stream) {
  const float* x   = (const float*)d_in[0];
  const float* adj = (const float*)d_in[1];
  const float* w   = (const float*)d_in[2];
  const float* wq  = (const float*)d_in[3];
  const float* wk  = (const float*)d_in[4];
  const float* wv  = (const float*)d_in[5];
  float* out = (float*)d_out;

  char* ws = (char*)d_ws;
  unsigned short* zb      = (unsigned short*)ws;                   // 24*2048*64*2 = 6,291,456
  float*          partial = (float*)(ws + 6291456);                // 4*24*2048*4  =   786,432
  float*          dw      = (float*)(ws + 6291456 + 786432);       // 64*4         =       256
  unsigned short* wT      = (unsigned short*)(ws + 6291456 + 786432 + 256);        // 24,576

  hipLaunchKernelGGL(prep,        dim3(NP + 64 + 1), dim3(256), 0, stream,
                     x, w, wq, wk, wv, zb, dw, wT);
  hipLaunchKernelGGL(gram_expsum, dim3(8, 4, 24),    dim3(256), 0, stream, zb, partial);
  hipLaunchKernelGGL(cross_attn,  dim3(500),         dim3(256), 0, stream,
                     x, wT, adj, partial, dw, out);
}

// Round 3
// 148.994 us; speedup vs baseline: 1.1268x; 1.0329x over previous
//
#include <hip/hip_runtime.h>
#include <hip/hip_bf16.h>

// Problem constants
#define N_   2000
#define NP   2048   // padded rows
#define F_   64
#define T_   24

typedef short  v8s  __attribute__((ext_vector_type(8)));   // 8 bf16 (4 VGPRs) MFMA frag
typedef float  v4f  __attribute__((ext_vector_type(4)));   // MFMA C/D frag
typedef float  v4f_ __attribute__((ext_vector_type(4)));
typedef unsigned short v4us __attribute__((ext_vector_type(4)));

// sqrt(log2(e)) in fp32: scaling Z1 by this makes the gram MFMA output
// already log2-domain, so exp(s) == exp2(C) with no per-element multiply.
#define ALPHA 1.2011224087864498f
#define E_CONST 2.718281828459045f

__device__ __forceinline__ unsigned short f2bf(float f) {
  unsigned int u = __float_as_uint(f);
  u += 0x7fffu + ((u >> 16) & 1u);     // RNE
  return (unsigned short)(u >> 16);
}

// ---------------------------------------------------------------------------
// Kernel 1 (fused prep):
//   blocks [0,2048):     fill_z  -> zb[t][n][f] = bf16(ALPHA * z1), pad n>=2000
//   blocks [2048,2112):  diag_w  -> dw[f] = sum_p weight[p][f][f]
//   block  2112:         prep_wT -> wT[m][fout][fin] bf16 (B-operand layout)
//   blocks [2113,2161):  zero rowsum (24*2048 floats) for gram's atomics
// ---------------------------------------------------------------------------
__global__ __launch_bounds__(256) void prep(const float* __restrict__ x,
                                            const float* __restrict__ w,
                                            const float* __restrict__ wq,
                                            const float* __restrict__ wk,
                                            const float* __restrict__ wv,
                                            unsigned short* __restrict__ zb,
                                            float* __restrict__ dw,
                                            unsigned short* __restrict__ wT,
                                            float* __restrict__ rowsum) {
  __shared__ float xs[F_ * 25];     // fill_z transpose buffer (stride 25)
  __shared__ float red[4];
  int b = blockIdx.x;
  int tid = threadIdx.x, wave = tid >> 6, lane = tid & 63;

  if (b < NP) {                                   // ---- fill_z ----
    int n = b;
    if (n >= N_) {
      for (int t = wave; t < T_; t += 4) zb[(t * NP + n) * F_ + lane] = 0;
      return;
    }
    const float* xn = x + n * (F_ * T_);
    for (int i = tid; i < F_ * T_; i += 256)
      xs[(i / T_) * 25 + (i % T_)] = xn[i];
    __syncthreads();
    for (int t = wave; t < T_; t += 4) {
      float v = xs[lane * 25 + t];    // f = lane
      float ss = v * v;
      #pragma unroll
      for (int m = 1; m < 64; m <<= 1) ss += __shfl_xor(ss, m);
      float nrm = fmaxf(sqrtf(ss), 1e-12f);
      zb[(t * NP + n) * F_ + lane] = f2bf(v / nrm * ALPHA);
    }
  } else if (b < NP + 64) {                       // ---- diag_w ----
    int f = b - NP;
    float s = 0.f;
    for (int p = tid; p < N_; p += 256) s += w[p * (F_ * F_) + f * (F_ + 1)];
    #pragma unroll
    for (int m = 1; m < 64; m <<= 1) s += __shfl_xor(s, m);
    if (lane == 0) red[wave] = s;
    __syncthreads();
    if (tid == 0) dw[f] = red[0] + red[1] + red[2] + red[3];
  } else if (b == NP + 64) {                      // ---- prep_wT ----
    for (int i = tid; i < 3 * 4096; i += 256) {
      int m = i >> 12, r = i & 4095;
      const float* src = (m == 0) ? wq : (m == 1) ? wk : wv;
      int fi = r >> 6, fo = r & 63;               // src[fi][fo]
      wT[m * 4096 + fo * 64 + fi] = f2bf(src[r]);
    }
  } else {                                        // ---- zero rowsum ----
    int blk = b - (NP + 65);                      // 0..47, 1024 floats each
    v4f_ z4 = {0.f, 0.f, 0.f, 0.f};
    *(v4f_*)(rowsum + blk * 1024 + tid * 4) = z4;
  }
}

// ---------------------------------------------------------------------------
// Kernel 2: symmetric gram exp-sum.
//   rowsum[t][r] += sum_c exp2(C[r][c])  where C = alpha^2 * (z1_r . z1_c)
// Upper-triangle 256x256 block pairs: grid (36 pairs, 24 t), block 256 = 4
// waves (64 rows each). Off-diagonal blocks also emit column sums (symmetry).
// True denominator sum_c exp(s-1) = rowsum / e, folded into cross_attn.
// ---------------------------------------------------------------------------
__global__ __launch_bounds__(256) void gram_expsum(const unsigned short* __restrict__ zb,
                                                   float* __restrict__ rowsum) {
  int p = blockIdx.x, t = blockIdx.y;
  int bi = 0;
  while (p >= 8 - bi) { p -= 8 - bi; bi++; }      // pair -> (bi, bj), bi<=bj
  int bj = bi + p;
  int wave = threadIdx.x >> 6, lane = threadIdx.x & 63;
  int lr = lane & 15, lk = (lane >> 4) * 8;
  const unsigned short* z = zb + t * (NP * F_);
  int r0 = bi * 256 + wave * 64;

  v8s a[4][2];
  #pragma unroll
  for (int rg = 0; rg < 4; rg++)
    #pragma unroll
    for (int kb = 0; kb < 2; kb++)
      a[rg][kb] = *(const v8s*)(z + (r0 + rg * 16 + lr) * F_ + kb * 32 + lk);

  float racc[16];
  #pragma unroll
  for (int i = 0; i < 16; i++) racc[i] = 0.f;

  int c0 = bj * 256;
  int c1 = (c0 + 256 > N_) ? N_ : c0 + 256;       // bj==7: 13 tiles (cols<2000)
  const unsigned short* bp = z + (c0 + lr) * F_ + lk;
  v4f cz = {0.f, 0.f, 0.f, 0.f};
  float* rs = rowsum + t * NP;
  bool offd = (bi != bj);

  for (int c = c0; c < c1; c += 16) {
    v8s b0 = *(const v8s*)(bp);
    v8s b1 = *(const v8s*)(bp + 32);
    bp += 16 * F_;
    float colacc = 0.f;
    #pragma unroll
    for (int rg = 0; rg < 4; rg++) {
      v4f C = __builtin_amdgcn_mfma_f32_16x16x32_bf16(a[rg][0], b0, cz, 0, 0, 0);
      C = __builtin_amdgcn_mfma_f32_16x16x32_bf16(a[rg][1], b1, C, 0, 0, 0);
      #pragma unroll
      for (int i = 0; i < 4; i++) {
        float e = __builtin_amdgcn_exp2f(C[i]);
        racc[rg * 4 + i] += e;
        colacc += e;
      }
    }
    if (offd) {                                    // column sums via symmetry
      colacc += __shfl_xor(colacc, 16);
      colacc += __shfl_xor(colacc, 32);
      if ((lane >> 4) == 0) atomicAdd(&rs[c + lr], colacc);
    }
  }
  // row sums: cols live in lane&15, reduce across those 16 lanes
  #pragma unroll
  for (int i = 0; i < 16; i++) {
    racc[i] += __shfl_xor(racc[i], 1);
    racc[i] += __shfl_xor(racc[i], 2);
    racc[i] += __shfl_xor(racc[i], 4);
    racc[i] += __shfl_xor(racc[i], 8);
  }
  if (lr == 0) {
    #pragma unroll
    for (int rg = 0; rg < 4; rg++)
      #pragma unroll
      for (int i = 0; i < 4; i++)
        atomicAdd(&rs[r0 + rg * 16 + (lane >> 4) * 4 + i], racc[rg * 4 + i]);
  }
}

// ---------------------------------------------------------------------------
// Kernel 3: cross-attention per n (one wave each) + inline diag_adj + store.
// Per-wave LDS region 16KB: xt[32][64] | q[32][64] | k[32][64] | vT[64][32],
// p[32][32] reuses xt. All bf16. Rows t>=24 zero-padded.
// ---------------------------------------------------------------------------
__global__ __launch_bounds__(256) void cross_attn(const float* __restrict__ x,
                                                  const unsigned short* __restrict__ wT,
                                                  const float* __restrict__ adj,
                                                  const float* __restrict__ rowsum,
                                                  const float* __restrict__ dw_g,
                                                  float* __restrict__ out) {
  __shared__ __align__(16) unsigned short lds[4 * 8192];
  int wave = threadIdx.x >> 6, lane = threadIdx.x & 63;
  int n = blockIdx.x * 4 + wave;
  unsigned short* xt = lds + wave * 8192;
  unsigned short* q  = xt + 2048;
  unsigned short* k  = xt + 4096;
  unsigned short* vT = xt + 6144;
  unsigned short* p  = xt;                      // reused after phase 1
  int lr = lane & 15, lk = (lane >> 4) * 8;
  int row0q = (lane >> 4) * 4;
  v4f cz = {0.f, 0.f, 0.f, 0.f};

  // ---- diag_adj[n] = adj[n][n] * e * sum_t 1/rowsum[t][n] ----
  float invsum = 0.f;
  if (lane < T_) invsum = 1.0f / rowsum[lane * NP + n];
  #pragma unroll
  for (int m = 1; m < 64; m <<= 1) invsum += __shfl_xor(invsum, m);
  float dadj = adj[n * (N_ + 1)] * E_CONST * invsum;

  // ---- load x[n] (F,T) -> xt (T,F) bf16, zero rows 24..31 ----
  const float* xn = x + n * (F_ * T_);
  #pragma unroll
  for (int j = 0; j < 24; j++) {
    int i = j * 64 + lane;
    float v = xn[i];
    xt[(i % T_) * 64 + (i / T_)] = f2bf(v);
  }
  { v8s z8 = {0,0,0,0,0,0,0,0}; *(v8s*)(xt + 24 * 64 + lane * 8) = z8; }

  // ---- phase 1: Q = xt*Wq, K = xt*Wk, V = xt*Wv ----
  v8s xa[2][2];
  #pragma unroll
  for (int rt = 0; rt < 2; rt++)
    #pragma unroll
    for (int kb = 0; kb < 2; kb++)
      xa[rt][kb] = *(const v8s*)(xt + (rt * 16 + lr) * 64 + kb * 32 + lk);

  #pragma unroll
  for (int m = 0; m < 3; m++) {
    const unsigned short* wt = wT + m * 4096;
    unsigned short* dst = (m == 0) ? q : k;
    #pragma unroll
    for (int ct = 0; ct < 4; ct++) {
      v8s b0 = *(const v8s*)(wt + (ct * 16 + lr) * 64 + lk);
      v8s b1 = *(const v8s*)(wt + (ct * 16 + lr) * 64 + 32 + lk);
      int col = ct * 16 + lr;
      #pragma unroll
      for (int rt = 0; rt < 2; rt++) {
        v4f C = __builtin_amdgcn_mfma_f32_16x16x32_bf16(xa[rt][0], b0, cz, 0, 0, 0);
        C = __builtin_amdgcn_mfma_f32_16x16x32_bf16(xa[rt][1], b1, C, 0, 0, 0);
        int r0 = rt * 16 + row0q;
        if (m < 2) {
          #pragma unroll
          for (int i = 0; i < 4; i++) dst[(r0 + i) * 64 + col] = f2bf(C[i]);
        } else {            // V stored transposed: vT[f][s], 4 contiguous bf16
          v4us pk = { f2bf(C[0]), f2bf(C[1]), f2bf(C[2]), f2bf(C[3]) };
          *(v4us*)(vT + col * 32 + r0) = pk;
        }
      }
    }
  }

  // ---- phase 2: scores = Q K^T / 8, softmax over s (mask s>=24), P -> LDS ----
  v8s qa[2][2];
  #pragma unroll
  for (int rt = 0; rt < 2; rt++)
    #pragma unroll
    for (int kb = 0; kb < 2; kb++)
      qa[rt][kb] = *(const v8s*)(q + (rt * 16 + lr) * 64 + kb * 32 + lk);

  float ev[2][2][4];   // [ct][rt][i]
  #pragma unroll
  for (int ct = 0; ct < 2; ct++) {
    v8s b0 = *(const v8s*)(k + (ct * 16 + lr) * 64 + lk);
    v8s b1 = *(const v8s*)(k + (ct * 16 + lr) * 64 + 32 + lk);
    int col = ct * 16 + lr;
    #pragma unroll
    for (int rt = 0; rt < 2; rt++) {
      v4f C = __builtin_amdgcn_mfma_f32_16x16x32_bf16(qa[rt][0], b0, cz, 0, 0, 0);
      C = __builtin_amdgcn_mfma_f32_16x16x32_bf16(qa[rt][1], b1, C, 0, 0, 0);
      #pragma unroll
      for (int i = 0; i < 4; i++)
        ev[ct][rt][i] = (col < T_) ? __expf(C[i] * 0.125f) : 0.0f;
    }
  }
  #pragma unroll
  for (int rt = 0; rt < 2; rt++)
    #pragma unroll
    for (int i = 0; i < 4; i++) {
      float r = ev[0][rt][i] + ev[1][rt][i];
      r += __shfl_xor(r, 1); r += __shfl_xor(r, 2);
      r += __shfl_xor(r, 4); r += __shfl_xor(r, 8);
      float inv = 1.0f / r;
      int row = rt * 16 + row0q + i;
      p[row * 32 + lr]      = f2bf(ev[0][rt][i] * inv);
      p[row * 32 + 16 + lr] = f2bf(ev[1][rt][i] * inv);
    }

  // ---- phase 3: O = P V, scale by diag_adj[n]*diag_w[f], store out[n][f][t] ----
  v8s pa[2];
  #pragma unroll
  for (int rt = 0; rt < 2; rt++)
    pa[rt] = *(const v8s*)(p + (rt * 16 + lr) * 32 + lk);
  float* outn = out + n * (F_ * T_);
  #pragma unroll
  for (int ct = 0; ct < 4; ct++) {
    v8s vb = *(const v8s*)(vT + (ct * 16 + lr) * 32 + lk);
    float sc = dadj * dw_g[ct * 16 + lr];
    #pragma unroll
    for (int rt = 0; rt < 2; rt++) {
      v4f C = __builtin_amdgcn_mfma_f32_16x16x32_bf16(pa[rt], vb, cz, 0, 0, 0);
      int r0 = rt * 16 + row0q;
      if (r0 < T_) {
        v4f o;
        #pragma unroll
        for (int i = 0; i < 4; i++) o[i] = C[i] * sc;
        *(v4f*)(outn + (ct * 16 + lr) * T_ + r0) = o;
      }
    }
  }
}

// ---------------------------------------------------------------------------
extern "C" void kernel_launch(void* const* d_in, const int* in_sizes, int n_in,
                              void* d_out, int out_size, void* d_ws, size_t ws_size,
                              hipStream_t stream) {
  const float* x   = (const float*)d_in[0];
  const float* adj = (const float*)d_in[1];
  const float* w   = (const float*)d_in[2];
  const float* wq  = (const float*)d_in[3];
  const float* wk  = (const float*)d_in[4];
  const float* wv  = (const float*)d_in[5];
  float* out = (float*)d_out;

  char* ws = (char*)d_ws;
  unsigned short* zb     = (unsigned short*)ws;                    // 24*2048*64*2 = 6,291,456
  float*          rowsum = (float*)(ws + 6291456);                 // 24*2048*4   =   196,608
  float*          dw     = (float*)(ws + 6291456 + 196608);        // 64*4        =       256
  unsigned short* wT     = (unsigned short*)(ws + 6291456 + 196608 + 256);   // 24,576

  hipLaunchKernelGGL(prep,        dim3(NP + 64 + 1 + 48), dim3(256), 0, stream,
                     x, w, wq, wk, wv, zb, dw, wT, rowsum);
  hipLaunchKernelGGL(gram_expsum, dim3(36, 24),           dim3(256), 0, stream, zb, rowsum);
  hipLaunchKernelGGL(cross_attn,  dim3(500),              dim3(256), 0, stream,
                     x, wT, adj, rowsum, dw, out);
}